// Round 2
// baseline (63.730 us; speedup 1.0000x reference)
//
#include <hip/hip_runtime.h>

// x: [16,128,128,64] f32 NHWC -> out: [16,128,128,128] (ax | ay)
constexpr int Hn = 128, Wn = 128, Cn = 64;
constexpr int CHUNK = 8;                      // w-pixels per thread (rolling window)

// Load one input column (3 rows x 4 channels) at width w, produce per-column
// aggregates: cs = e(h-1)+e(h)+e(h+1), cyv = e(h) + 2*e(h+1).  OOB -> exp(0)=1.
__device__ __forceinline__ void load_col(const float* __restrict__ rowp,
                                         int h, int w,
                                         float cs[4], float cyv[4]) {
    float4 v0 = make_float4(0.f, 0.f, 0.f, 0.f), v1 = v0, v2 = v0;
    if ((unsigned)w < (unsigned)Wn) {
        const float* p = rowp + (w << 6);
        if (h > 0)      v0 = *reinterpret_cast<const float4*>(p - (Wn << 6));
        v1 = *reinterpret_cast<const float4*>(p);
        if (h < Hn - 1) v2 = *reinterpret_cast<const float4*>(p + (Wn << 6));
    }
    float e0, e1, e2;
    e0 = __expf(v0.x); e1 = __expf(v1.x); e2 = __expf(v2.x);
    cs[0] = e0 + e1 + e2;  cyv[0] = fmaf(2.f, e2, e1);
    e0 = __expf(v0.y); e1 = __expf(v1.y); e2 = __expf(v2.y);
    cs[1] = e0 + e1 + e2;  cyv[1] = fmaf(2.f, e2, e1);
    e0 = __expf(v0.z); e1 = __expf(v1.z); e2 = __expf(v2.z);
    cs[2] = e0 + e1 + e2;  cyv[2] = fmaf(2.f, e2, e1);
    e0 = __expf(v0.w); e1 = __expf(v1.w); e2 = __expf(v2.w);
    cs[3] = e0 + e1 + e2;  cyv[3] = fmaf(2.f, e2, e1);
}

__global__ __launch_bounds__(256) void cartpool_kernel(const float* __restrict__ x,
                                                       float* __restrict__ out) {
    // One block per (b,h) row: 16 chunks (w) x 16 channel-groups (c4).
    const int c4    = (threadIdx.x & 15) << 2;   // channel offset 0..60
    const int chunk = threadIdx.x >> 4;          // 0..15
    const int row   = blockIdx.x;                // b*H + h
    const int h     = row & (Hn - 1);
    const int w0    = chunk * CHUNK;

    const float* rowp = x   + ((size_t)row << 13) + c4;   // row*W*C
    float*       orow = out + ((size_t)row << 14) + c4;   // row*W*2C

    float cs[3][4], cy[3][4];
    load_col(rowp, h, w0 - 1, cs[0], cy[0]);
    load_col(rowp, h, w0,     cs[1], cy[1]);

    #pragma unroll
    for (int s = 0; s < CHUNK; ++s) {
        const int i0 = s % 3, i1 = (s + 1) % 3, i2 = (s + 2) % 3;  // static after unroll
        load_col(rowp, h, w0 + s + 1, cs[i2], cy[i2]);
        const int w = w0 + s;

        float ax[4], ay[4];
        #pragma unroll
        for (int q = 0; q < 4; ++q) {
            const float S   = cs[i0][q] + cs[i1][q] + cs[i2][q];
            const float sy  = cy[i0][q] + cy[i1][q] + cy[i2][q];
            const float sx  = fmaf(2.f, cs[i2][q], cs[i1][q]);
            const float inv = __builtin_amdgcn_rcpf(S);
            ax[q] = (fmaf(sx, inv, -1.f) + (float)w) * (1.f / Wn);
            ay[q] = (fmaf(sy, inv, -1.f) + (float)h) * (1.f / Hn);
        }
        float* ob = orow + ((size_t)w << 7);
        *reinterpret_cast<float4*>(ob)      = make_float4(ax[0], ax[1], ax[2], ax[3]);
        *reinterpret_cast<float4*>(ob + Cn) = make_float4(ay[0], ay[1], ay[2], ay[3]);
    }
}

extern "C" void kernel_launch(void* const* d_in, const int* in_sizes, int n_in,
                              void* d_out, int out_size, void* d_ws, size_t ws_size,
                              hipStream_t stream) {
    const float* x = (const float*)d_in[0];
    float* out = (float*)d_out;
    const int grid = 16 * Hn;                 // one block per (b,h) row = 2048
    cartpool_kernel<<<grid, 256, 0, stream>>>(x, out);
}

// Round 3
// 38.278 us; speedup vs baseline: 1.6649x; 1.6649x over previous
//
#include <hip/hip_runtime.h>

// x: [16,128,128,64] f32 NHWC -> out: [16,128,128,128] (ax | ay)
constexpr int Hn = 128, Wn = 128, Cn = 64;

typedef float f4v __attribute__((ext_vector_type(4)));

__device__ __forceinline__ f4v ld4(const float* __restrict__ p) {
    return *reinterpret_cast<const f4v*>(p);
}

__device__ __forceinline__ f4v exp4(f4v a) {
    f4v r;
    r.x = __expf(a.x); r.y = __expf(a.y); r.z = __expf(a.z); r.w = __expf(a.w);
    return r;
}

__global__ __launch_bounds__(256) void cartpool_kernel(const float* __restrict__ x,
                                                       float* __restrict__ out) {
    const int row = blockIdx.y;                  // b*H + h
    const int h   = row & (Hn - 1);
    const int b   = row >> 7;
    const int w   = (blockIdx.x << 4) + (threadIdx.x >> 4);  // 16 pixels / block
    const int c4  = (threadIdx.x & 15) << 2;

    const float* p = x + ((size_t)row << 13) + (w << 6) + c4;

    f4v v0, v1, v2, v3, v4, v5, v6, v7, v8;

    if (h > 0 && h < Hn - 1 && w > 0 && w < Wn - 1) {
        // Fast path: 9 unconditional loads, issued back-to-back.
        const float* qm = p - (Wn << 6) - Cn;    // (h-1, w-1)
        const float* q0 = p - Cn;                // (h,   w-1)
        const float* qp = p + (Wn << 6) - Cn;    // (h+1, w-1)
        v0 = ld4(qm); v1 = ld4(qm + Cn); v2 = ld4(qm + 2 * Cn);
        v3 = ld4(q0); v4 = ld4(q0 + Cn); v5 = ld4(q0 + 2 * Cn);
        v6 = ld4(qp); v7 = ld4(qp + Cn); v8 = ld4(qp + 2 * Cn);
    } else {
        // Border path (~4% of waves): checked loads, OOB -> 0 (exp(0)=1 joins softmax).
        f4v t[9];
        #pragma unroll
        for (int pp = 0; pp < 9; ++pp) {
            const int hh = h + pp / 3 - 1;
            const int ww = w + pp % 3 - 1;
            f4v z = {0.f, 0.f, 0.f, 0.f};
            t[pp] = z;
            if (((unsigned)hh < (unsigned)Hn) && ((unsigned)ww < (unsigned)Wn))
                t[pp] = ld4(x + (((size_t)(b * Hn + hh)) << 13) + (ww << 6) + c4);
        }
        v0 = t[0]; v1 = t[1]; v2 = t[2]; v3 = t[3]; v4 = t[4];
        v5 = t[5]; v6 = t[6]; v7 = t[7]; v8 = t[8];
    }

    const f4v e0 = exp4(v0), e1 = exp4(v1), e2 = exp4(v2);
    const f4v e3 = exp4(v3), e4 = exp4(v4), e5 = exp4(v5);
    const f4v e6 = exp4(v6), e7 = exp4(v7), e8 = exp4(v8);

    // wx = col index (0,1,2), wy = row index (0,1,2), pattern p = 3*wy + wx
    const f4v S  = e0 + e1 + e2 + e3 + e4 + e5 + e6 + e7 + e8;
    const f4v sx = e1 + e4 + e7 + 2.0f * (e2 + e5 + e8);
    const f4v sy = e3 + e4 + e5 + 2.0f * (e6 + e7 + e8);

    f4v inv;
    inv.x = __builtin_amdgcn_rcpf(S.x);
    inv.y = __builtin_amdgcn_rcpf(S.y);
    inv.z = __builtin_amdgcn_rcpf(S.z);
    inv.w = __builtin_amdgcn_rcpf(S.w);

    const f4v ax = (sx * inv - 1.0f + (float)w) * (1.0f / Wn);
    const f4v ay = (sy * inv - 1.0f + (float)h) * (1.0f / Hn);

    float* ob = out + ((size_t)row << 14) + (w << 7) + c4;
    __builtin_nontemporal_store(ax, reinterpret_cast<f4v*>(ob));
    __builtin_nontemporal_store(ay, reinterpret_cast<f4v*>(ob + Cn));
}

extern "C" void kernel_launch(void* const* d_in, const int* in_sizes, int n_in,
                              void* d_out, int out_size, void* d_ws, size_t ws_size,
                              hipStream_t stream) {
    const float* x = (const float*)d_in[0];
    float* out = (float*)d_out;
    dim3 grid(8, 16 * Hn);                     // 8 blocks per (b,h) row
    cartpool_kernel<<<grid, 256, 0, stream>>>(x, out);
}

// Round 4
// 35.745 us; speedup vs baseline: 1.7829x; 1.0708x over previous
//
#include <hip/hip_runtime.h>

// x: [16,128,128,64] f32 NHWC -> out: [16,128,128,128] (ax | ay)
// One thread = 2 vertically-adjacent pixels x 4 channels.
constexpr int Hn = 128, Wn = 128, Cn = 64;

typedef float f4v __attribute__((ext_vector_type(4)));

__device__ __forceinline__ f4v ld4(const float* __restrict__ p) {
    return *reinterpret_cast<const f4v*>(p);
}

__device__ __forceinline__ f4v exp4(f4v a) {
    f4v r;
    r.x = __expf(a.x); r.y = __expf(a.y); r.z = __expf(a.z); r.w = __expf(a.w);
    return r;
}

__global__ __launch_bounds__(256) void cartpool_kernel(const float* __restrict__ x,
                                                       float* __restrict__ out) {
    const int pairrow = blockIdx.y;              // b*64 + hp
    const int hp = pairrow & 63;
    const int b  = pairrow >> 6;
    const int h0 = hp << 1;                      // even row; pair = (h0, h0+1)
    const int w  = (blockIdx.x << 4) + (threadIdx.x >> 4);
    const int c4 = (threadIdx.x & 15) << 2;

    constexpr size_t RS = (size_t)Wn * Cn;       // input row stride (8192 floats)
    const float* p = x + ((size_t)(b * Hn + h0)) * RS + (w << 6) + c4;

    // V[r][j]: input rows h0-1 .. h0+2, cols w-1 .. w+1
    f4v V[4][3];
    if (h0 > 0 && h0 < Hn - 2 && w > 0 && w < Wn - 1) {
        const float* q = p - RS - Cn;
        #pragma unroll
        for (int r = 0; r < 4; ++r) {
            V[r][0] = ld4(q); V[r][1] = ld4(q + Cn); V[r][2] = ld4(q + 2 * Cn);
            q += RS;
        }
    } else {
        #pragma unroll
        for (int r = 0; r < 4; ++r) {
            const int hh = h0 + r - 1;
            #pragma unroll
            for (int j = 0; j < 3; ++j) {
                const int ww = w + j - 1;
                f4v z = {0.f, 0.f, 0.f, 0.f};
                V[r][j] = z;
                if (((unsigned)hh < (unsigned)Hn) && ((unsigned)ww < (unsigned)Wn))
                    V[r][j] = ld4(x + ((size_t)(b * Hn + hh)) * RS + (ww << 6) + c4);
            }
        }
    }

    f4v E[4][3];
    #pragma unroll
    for (int r = 0; r < 4; ++r)
        #pragma unroll
        for (int j = 0; j < 3; ++j) E[r][j] = exp4(V[r][j]);

    // Pixel A = row h0 (window rows 0..2), pixel B = row h0+1 (window rows 1..3).
    f4v SA = {0.f,0.f,0.f,0.f}, SB = SA, sxA = SA, sxB = SA, syA = SA, syB = SA;
    #pragma unroll
    for (int j = 0; j < 3; ++j) {
        const f4v e12 = E[1][j] + E[2][j];
        const f4v csA = E[0][j] + e12;           // col sum for A
        const f4v csB = e12 + E[3][j];           // col sum for B
        SA += csA; SB += csB;
        syA += E[1][j] + 2.0f * E[2][j];         // wy weights within A's window
        syB += E[2][j] + 2.0f * E[3][j];
        if (j == 1) { sxA = csA;  sxB = csB; }
        if (j == 2) { sxA += 2.0f * csA;  sxB += 2.0f * csB; }
    }

    f4v invA, invB;
    invA.x = __builtin_amdgcn_rcpf(SA.x); invA.y = __builtin_amdgcn_rcpf(SA.y);
    invA.z = __builtin_amdgcn_rcpf(SA.z); invA.w = __builtin_amdgcn_rcpf(SA.w);
    invB.x = __builtin_amdgcn_rcpf(SB.x); invB.y = __builtin_amdgcn_rcpf(SB.y);
    invB.z = __builtin_amdgcn_rcpf(SB.z); invB.w = __builtin_amdgcn_rcpf(SB.w);

    const f4v axA = (sxA * invA - 1.0f + (float)w)        * (1.0f / Wn);
    const f4v ayA = (syA * invA - 1.0f + (float)h0)       * (1.0f / Hn);
    const f4v axB = (sxB * invB - 1.0f + (float)w)        * (1.0f / Wn);
    const f4v ayB = (syB * invB - 1.0f + (float)(h0 + 1)) * (1.0f / Hn);

    constexpr size_t ORS = (size_t)Wn * 2 * Cn;  // output row stride (16384 floats)
    float* obA = out + ((size_t)(b * Hn + h0)) * ORS + (w << 7) + c4;
    float* obB = obA + ORS;
    __builtin_nontemporal_store(axA, reinterpret_cast<f4v*>(obA));
    __builtin_nontemporal_store(ayA, reinterpret_cast<f4v*>(obA + Cn));
    __builtin_nontemporal_store(axB, reinterpret_cast<f4v*>(obB));
    __builtin_nontemporal_store(ayB, reinterpret_cast<f4v*>(obB + Cn));
}

extern "C" void kernel_launch(void* const* d_in, const int* in_sizes, int n_in,
                              void* d_out, int out_size, void* d_ws, size_t ws_size,
                              hipStream_t stream) {
    const float* x = (const float*)d_in[0];
    float* out = (float*)d_out;
    dim3 grid(8, 16 * (Hn / 2));                 // 8 w-stripes x 1024 pair-rows
    cartpool_kernel<<<grid, 256, 0, stream>>>(x, out);
}

// Round 5
// 35.473 us; speedup vs baseline: 1.7966x; 1.0077x over previous
//
#include <hip/hip_runtime.h>

// x: [16,128,128,64] f32 NHWC -> out: [16,128,128,128] (ax | ay)
// One thread = 2x2 pixel tile x 4 channels (loads 4x4 neighborhood).
constexpr int Hn = 128, Wn = 128, Cn = 64;

typedef float f4v __attribute__((ext_vector_type(4)));

__device__ __forceinline__ f4v ld4(const float* __restrict__ p) {
    return *reinterpret_cast<const f4v*>(p);
}

__device__ __forceinline__ f4v exp4(f4v a) {
    f4v r;
    r.x = __expf(a.x); r.y = __expf(a.y); r.z = __expf(a.z); r.w = __expf(a.w);
    return r;
}

__device__ __forceinline__ f4v rcp4(f4v a) {
    f4v r;
    r.x = __builtin_amdgcn_rcpf(a.x); r.y = __builtin_amdgcn_rcpf(a.y);
    r.z = __builtin_amdgcn_rcpf(a.z); r.w = __builtin_amdgcn_rcpf(a.w);
    return r;
}

__global__ __launch_bounds__(128) void cartpool_kernel(const float* __restrict__ x,
                                                       float* __restrict__ out) {
    const int pairrow = blockIdx.y;              // b*64 + hp
    const int hp = pairrow & 63;
    const int b  = pairrow >> 6;
    const int h0 = hp << 1;                      // rows (h0, h0+1)
    const int w0 = (blockIdx.x << 4) + ((threadIdx.x >> 4) << 1);  // cols (w0, w0+1)
    const int c4 = (threadIdx.x & 15) << 2;

    constexpr size_t RS = (size_t)Wn * Cn;       // 8192 floats
    const float* p = x + ((size_t)(b * Hn + h0)) * RS + (w0 << 6) + c4;

    // E[r][j]: rows h0-1..h0+2, cols w0-1..w0+2
    f4v E[4][4];
    if (h0 >= 2 && h0 <= 124 && w0 >= 2 && w0 <= 124) {
        const float* q = p - RS - Cn;
        #pragma unroll
        for (int r = 0; r < 4; ++r) {
            E[r][0] = ld4(q); E[r][1] = ld4(q + Cn);
            E[r][2] = ld4(q + 2 * Cn); E[r][3] = ld4(q + 3 * Cn);
            q += RS;
        }
    } else {
        #pragma unroll
        for (int r = 0; r < 4; ++r) {
            const int hh = h0 + r - 1;
            #pragma unroll
            for (int j = 0; j < 4; ++j) {
                const int ww = w0 + j - 1;
                f4v z = {0.f, 0.f, 0.f, 0.f};
                E[r][j] = z;
                if (((unsigned)hh < (unsigned)Hn) && ((unsigned)ww < (unsigned)Wn))
                    E[r][j] = ld4(x + ((size_t)(b * Hn + hh)) * RS + (ww << 6) + c4);
            }
        }
    }

    #pragma unroll
    for (int r = 0; r < 4; ++r)
        #pragma unroll
        for (int j = 0; j < 4; ++j) E[r][j] = exp4(E[r][j]);

    // Per-column aggregates (shared by the 2x2 pixels).
    f4v cSA[4], cSB[4], cYA[4], cYB[4];
    #pragma unroll
    for (int j = 0; j < 4; ++j) {
        const f4v e12 = E[1][j] + E[2][j];
        cSA[j] = E[0][j] + e12;                  // rows 0..2 sum (A = row h0)
        cSB[j] = e12 + E[3][j];                  // rows 1..3 sum (B = row h0+1)
        cYA[j] = fmaf(2.0f, E[2][j].x, E[1][j].x),
        cYA[j].x = fmaf(2.0f, E[2][j].x, E[1][j].x);
        cYA[j].y = fmaf(2.0f, E[2][j].y, E[1][j].y);
        cYA[j].z = fmaf(2.0f, E[2][j].z, E[1][j].z);
        cYA[j].w = fmaf(2.0f, E[2][j].w, E[1][j].w);
        cYB[j].x = fmaf(2.0f, E[3][j].x, E[2][j].x);
        cYB[j].y = fmaf(2.0f, E[3][j].y, E[2][j].y);
        cYB[j].z = fmaf(2.0f, E[3][j].z, E[2][j].z);
        cYB[j].w = fmaf(2.0f, E[3][j].w, E[2][j].w);
    }

    // 4 output pixels: A/B (row) x L/R (col). L uses cols 0..2, R uses 1..3.
    const f4v SAL = cSA[0] + cSA[1] + cSA[2], SAR = cSA[1] + cSA[2] + cSA[3];
    const f4v SBL = cSB[0] + cSB[1] + cSB[2], SBR = cSB[1] + cSB[2] + cSB[3];
    const f4v sxAL = cSA[1] + 2.0f * cSA[2],  sxAR = cSA[2] + 2.0f * cSA[3];
    const f4v sxBL = cSB[1] + 2.0f * cSB[2],  sxBR = cSB[2] + 2.0f * cSB[3];
    const f4v syAL = cYA[0] + cYA[1] + cYA[2], syAR = cYA[1] + cYA[2] + cYA[3];
    const f4v syBL = cYB[0] + cYB[1] + cYB[2], syBR = cYB[1] + cYB[2] + cYB[3];

    const f4v iAL = rcp4(SAL), iAR = rcp4(SAR), iBL = rcp4(SBL), iBR = rcp4(SBR);

    const float fw0 = (float)w0, fw1 = (float)(w0 + 1);
    const float fh0 = (float)h0, fh1 = (float)(h0 + 1);
    const f4v axAL = (sxAL * iAL - 1.0f + fw0) * (1.0f / Wn);
    const f4v ayAL = (syAL * iAL - 1.0f + fh0) * (1.0f / Hn);
    const f4v axAR = (sxAR * iAR - 1.0f + fw1) * (1.0f / Wn);
    const f4v ayAR = (syAR * iAR - 1.0f + fh0) * (1.0f / Hn);
    const f4v axBL = (sxBL * iBL - 1.0f + fw0) * (1.0f / Wn);
    const f4v ayBL = (syBL * iBL - 1.0f + fh1) * (1.0f / Hn);
    const f4v axBR = (sxBR * iBR - 1.0f + fw1) * (1.0f / Wn);
    const f4v ayBR = (syBR * iBR - 1.0f + fh1) * (1.0f / Hn);

    constexpr size_t ORS = (size_t)Wn * 2 * Cn;  // 16384 floats
    float* oA = out + ((size_t)(b * Hn + h0)) * ORS + (w0 << 7) + c4;
    float* oB = oA + ORS;
    __builtin_nontemporal_store(axAL, reinterpret_cast<f4v*>(oA));
    __builtin_nontemporal_store(ayAL, reinterpret_cast<f4v*>(oA + Cn));
    __builtin_nontemporal_store(axAR, reinterpret_cast<f4v*>(oA + 2 * Cn));
    __builtin_nontemporal_store(ayAR, reinterpret_cast<f4v*>(oA + 3 * Cn));
    __builtin_nontemporal_store(axBL, reinterpret_cast<f4v*>(oB));
    __builtin_nontemporal_store(ayBL, reinterpret_cast<f4v*>(oB + Cn));
    __builtin_nontemporal_store(axBR, reinterpret_cast<f4v*>(oB + 2 * Cn));
    __builtin_nontemporal_store(ayBR, reinterpret_cast<f4v*>(oB + 3 * Cn));
}

extern "C" void kernel_launch(void* const* d_in, const int* in_sizes, int n_in,
                              void* d_out, int out_size, void* d_ws, size_t ws_size,
                              hipStream_t stream) {
    const float* x = (const float*)d_in[0];
    float* out = (float*)d_out;
    dim3 grid(8, 16 * (Hn / 2));                 // 8 w-stripes x 1024 pair-rows
    cartpool_kernel<<<grid, 128, 0, stream>>>(x, out);
}